// Round 4
// baseline (77.957 us; speedup 1.0000x reference)
//
#include <hip/hip_runtime.h>
#include <hip/hip_fp16.h>

typedef _Float16 half8 __attribute__((ext_vector_type(8)));
typedef float floatx4 __attribute__((ext_vector_type(4)));

#define KH 256            // H (inner / K dim)
#define NN 1024           // N heads
#define BM 64             // b-rows per block (4 waves x 16)
#define NSPLIT 4          // split N across blockIdx.y
#define GPB 16            // 16-col groups per block (64/NSPLIT)

// ---------------- pack kernel: W fp32 -> f16, MFMA-fragment order ----------
// packed f16 index: ((g*8 + ks)*64 + lane)*8 + j
//   where n = g*16 + (lane&15), k = ks*32 + (lane>>4)*8 + j
__global__ __launch_bounds__(256)
void pack_w(const float* __restrict__ W, _Float16* __restrict__ P) {
    const int u  = blockIdx.x * 256 + threadIdx.x;   // 32768 threads total
    const int g  = u >> 9;
    const int ks = (u >> 6) & 7;
    const int l  = u & 63;
    const int n  = g * 16 + (l & 15);
    const int kb = ks * 32 + ((l >> 4) << 3);
    const float* src = W + (size_t)n * KH + kb;
    floatx4 lo = *(const floatx4*)src;
    floatx4 hi = *(const floatx4*)(src + 4);
    half8 h;
    h[0] = (_Float16)lo[0]; h[1] = (_Float16)lo[1];
    h[2] = (_Float16)lo[2]; h[3] = (_Float16)lo[3];
    h[4] = (_Float16)hi[0]; h[5] = (_Float16)hi[1];
    h[6] = (_Float16)hi[2]; h[7] = (_Float16)hi[3];
    *(half8*)(P + (size_t)u * 8) = h;                // fully coalesced 16B/lane
}

// ---------------- main kernel: reg-dbuf GEMM phase, store burst at end -----
__global__ __launch_bounds__(256, 2)
void lfh_main(const float* __restrict__ x, const _Float16* __restrict__ P,
              const float* __restrict__ bias, float* __restrict__ out) {
    const int t   = threadIdx.x;
    const int w   = t >> 6;
    const int l   = t & 63;
    const int l15 = l & 15;
    const int lq  = l >> 4;
    const int brow = blockIdx.x * BM + w * 16 + l15;
    const int g0   = blockIdx.y * GPB;

    // ---- A fragments (x rows), fp32 -> f16, kept in registers -------------
    half8 afrag[8];
    {
        const float* xr = x + (size_t)brow * KH;
        #pragma unroll
        for (int ks = 0; ks < 8; ++ks) {
            const int kb = ks * 32 + lq * 8;
            floatx4 lo = *(const floatx4*)(xr + kb);
            floatx4 hi = *(const floatx4*)(xr + kb + 4);
            half8 f;
            f[0] = (_Float16)lo[0]; f[1] = (_Float16)lo[1];
            f[2] = (_Float16)lo[2]; f[3] = (_Float16)lo[3];
            f[4] = (_Float16)hi[0]; f[5] = (_Float16)hi[1];
            f[6] = (_Float16)hi[2]; f[7] = (_Float16)hi[3];
            afrag[ks] = f;
        }
    }

    // fragment base for group g, slice ks: P + g*4096 + ks*512 + l*8 (f16)
    const _Float16* fb0 = P + (size_t)g0 * 4096 + (size_t)l * 8;

    // ---- GEMM phase: loads only in the VMEM stream, reg double-buffer -----
    half8 wf[2][8];
    #pragma unroll
    for (int ks = 0; ks < 8; ++ks)
        wf[0][ks] = *(const half8*)(fb0 + ks * 512);

    floatx4 acc[GPB];
    #pragma unroll
    for (int g = 0; g < GPB; ++g) {
        if (g + 1 < GPB) {                       // prefetch next group's frags
            const _Float16* fb = fb0 + (size_t)(g + 1) * 4096;
            #pragma unroll
            for (int ks = 0; ks < 8; ++ks)
                wf[(g + 1) & 1][ks] = *(const half8*)(fb + ks * 512);
        }
        floatx4 a = (floatx4)0.0f;
        #pragma unroll
        for (int ks = 0; ks < 8; ++ks)
            a = __builtin_amdgcn_mfma_f32_16x16x32_f16(wf[g & 1][ks], afrag[ks], a, 0, 0, 0);
        acc[g] = a;
        // pure rendezvous (no LDS, no waitcnt semantics): keeps the 4 waves'
        // identical W-fragment streams inside the 32KB L1 window
        if ((g & 1) == 1) __builtin_amdgcn_s_barrier();
    }

    // ---- store burst: nothing waits on these, drain at HBM rate -----------
    float* orow = out + (size_t)brow * NN;
    #pragma unroll
    for (int g = 0; g < GPB; ++g) {
        const int nb = (g0 + g) * 16 + lq * 4;
        floatx4 bv = *(const floatx4*)(bias + nb);
        floatx4 r;
        #pragma unroll
        for (int j = 0; j < 4; ++j) {
            const float z = acc[g][j] + bv[j];
            r[j] = __builtin_amdgcn_rcpf(1.0f + __expf(-z));
        }
        __builtin_nontemporal_store(r, (floatx4*)(orow + nb));
    }
}

extern "C" void kernel_launch(void* const* d_in, const int* in_sizes, int n_in,
                              void* d_out, int out_size, void* d_ws, size_t ws_size,
                              hipStream_t stream) {
    const float* x = (const float*)d_in[0];
    const float* W = (const float*)d_in[1];
    const float* b = (const float*)d_in[2];
    float* out = (float*)d_out;
    _Float16* P = (_Float16*)d_ws;            // 512 KB packed f16 W

    pack_w<<<dim3(128), dim3(256), 0, stream>>>(W, P);

    const int Btot = in_sizes[0] / KH;        // 32768
    lfh_main<<<dim3(Btot / BM, NSPLIT), dim3(256), 0, stream>>>(x, P, b, out);
}

// Round 5
// 70.211 us; speedup vs baseline: 1.1103x; 1.1103x over previous
//
#include <hip/hip_runtime.h>
#include <hip/hip_fp16.h>

typedef _Float16 half8 __attribute__((ext_vector_type(8)));
typedef float floatx4 __attribute__((ext_vector_type(4)));

#define KH 256              // H (inner / K dim)
#define NN 1024             // N heads
#define BM 128              // b-rows per block (8 waves x 16)
#define THREADS 512
#define NSPLIT 8            // N-split across blockIdx.y
#define GPB 8               // 16-col groups per block (64/NSPLIT)
#define GF16 4096           // f16 per packed group (16 n x 256 k)
#define WSLICE (GPB * GF16) // 32768 f16 = 64 KB LDS

// ---------------- pack kernel: W fp32 -> f16, MFMA-fragment order ----------
// packed f16 index: ((g*8 + ks)*64 + lane)*8 + j
//   where n = g*16 + (lane&15), k = ks*32 + (lane>>4)*8 + j
__global__ __launch_bounds__(256)
void pack_w(const float* __restrict__ W, _Float16* __restrict__ P) {
    const int u  = blockIdx.x * 256 + threadIdx.x;   // 32768 threads total
    const int g  = u >> 9;
    const int ks = (u >> 6) & 7;
    const int l  = u & 63;
    const int n  = g * 16 + (l & 15);
    const int kb = ks * 32 + ((l >> 4) << 3);
    const float* src = W + (size_t)n * KH + kb;
    floatx4 lo = *(const floatx4*)src;
    floatx4 hi = *(const floatx4*)(src + 4);
    half8 h;
    h[0] = (_Float16)lo[0]; h[1] = (_Float16)lo[1];
    h[2] = (_Float16)lo[2]; h[3] = (_Float16)lo[3];
    h[4] = (_Float16)hi[0]; h[5] = (_Float16)hi[1];
    h[6] = (_Float16)hi[2]; h[7] = (_Float16)hi[3];
    *(half8*)(P + (size_t)u * 8) = h;                // fully coalesced 16B/lane
}

// -------- main kernel: stage-once LDS, ONE barrier, free-running stores ----
__global__ __launch_bounds__(THREADS, 2)
void lfh_main(const float* __restrict__ x, const _Float16* __restrict__ P,
              const float* __restrict__ bias, float* __restrict__ out) {
    __shared__ _Float16 Ws[WSLICE];          // 64 KB, single buffer

    const int t   = threadIdx.x;
    const int w   = t >> 6;
    const int l   = t & 63;
    const int l15 = l & 15;
    const int lq  = l >> 4;
    const int brow = blockIdx.x * BM + w * 16 + l15;
    const int g0   = blockIdx.y * GPB;

    // ---- stage this block's 64KB W slice: 8 x (512 threads x 16B), async --
    {
        const _Float16* gsrc = P + (size_t)g0 * GF16;
        #pragma unroll
        for (int r = 0; r < 8; ++r) {
            __builtin_amdgcn_global_load_lds(
                (const __attribute__((address_space(1))) void*)(gsrc + r * 4096 + t * 8),
                (__attribute__((address_space(3))) void*)(Ws + r * 4096 + t * 8),
                16, 0, 0);
        }
    }

    // ---- A fragments (x rows), fp32 -> f16, in registers (overlaps stage) -
    half8 afrag[8];
    {
        const float* xr = x + (size_t)brow * KH;
        #pragma unroll
        for (int ks = 0; ks < 8; ++ks) {
            const int kb = ks * 32 + lq * 8;
            floatx4 lo = *(const floatx4*)(xr + kb);
            floatx4 hi = *(const floatx4*)(xr + kb + 4);
            half8 f;
            f[0] = (_Float16)lo[0]; f[1] = (_Float16)lo[1];
            f[2] = (_Float16)lo[2]; f[3] = (_Float16)lo[3];
            f[4] = (_Float16)hi[0]; f[5] = (_Float16)hi[1];
            f[6] = (_Float16)hi[2]; f[7] = (_Float16)hi[3];
            afrag[ks] = f;
        }
    }

    __syncthreads();   // the ONLY barrier: staged W visible to all waves

    float* orow = out + (size_t)brow * NN;
    #pragma unroll
    for (int g = 0; g < GPB; ++g) {
        // linear conflict-free fragment reads: each lane its own 16B slot
        const _Float16* fb = Ws + g * GF16 + l * 8;
        floatx4 acc = (floatx4)0.0f;
        #pragma unroll
        for (int ks = 0; ks < 8; ++ks) {
            half8 wf = *(const half8*)(fb + ks * 512);
            // swapped operands: D col = b-row (lane&15), D row = n_local
            acc = __builtin_amdgcn_mfma_f32_16x16x32_f16(wf, afrag[ks], acc, 0, 0, 0);
        }
        const int nb = (g0 + g) * 16 + lq * 4;
        floatx4 bv = *(const floatx4*)(bias + nb);
        floatx4 r;
        #pragma unroll
        for (int j = 0; j < 4; ++j) {
            const float z = acc[j] + bv[j];
            r[j] = __builtin_amdgcn_rcpf(1.0f + __expf(-z));
        }
        // fire-and-forget: no barrier ever waits on these
        __builtin_nontemporal_store(r, (floatx4*)(orow + nb));
    }
}

extern "C" void kernel_launch(void* const* d_in, const int* in_sizes, int n_in,
                              void* d_out, int out_size, void* d_ws, size_t ws_size,
                              hipStream_t stream) {
    const float* x = (const float*)d_in[0];
    const float* W = (const float*)d_in[1];
    const float* b = (const float*)d_in[2];
    float* out = (float*)d_out;
    _Float16* P = (_Float16*)d_ws;            // 512 KB packed f16 W

    pack_w<<<dim3(128), dim3(256), 0, stream>>>(W, P);

    const int Btot = in_sizes[0] / KH;        // 32768
    lfh_main<<<dim3(Btot / BM, NSPLIT), dim3(THREADS), 0, stream>>>(x, P, b, out);
}

// Round 6
// 65.234 us; speedup vs baseline: 1.1950x; 1.0763x over previous
//
#include <hip/hip_runtime.h>
#include <hip/hip_fp16.h>

typedef _Float16 half8 __attribute__((ext_vector_type(8)));
typedef float floatx4 __attribute__((ext_vector_type(4)));

#define KH 256              // H (inner / K dim)
#define NN 1024             // N heads
#define BM 64               // b-rows per block (4 waves x 16)
#define THREADS 256
#define NSPLIT 4            // N-split: block owns 256 output cols
#define GPB 16              // 16-col groups per block
#define GF16 4096           // f16 per packed group (16 n x 256 k)
#define LDSF 260            // padded f32 per out row in bounce tile

// ---------------- pack kernel: W fp32 -> f16, MFMA-fragment order ----------
// packed f16 index: ((g*8 + ks)*64 + lane)*8 + j
//   where n = g*16 + (lane&15), k = ks*32 + (lane>>4)*8 + j
__global__ __launch_bounds__(256)
void pack_w(const float* __restrict__ W, _Float16* __restrict__ P) {
    const int u  = blockIdx.x * 256 + threadIdx.x;   // 32768 threads total
    const int g  = u >> 9;
    const int ks = (u >> 6) & 7;
    const int l  = u & 63;
    const int n  = g * 16 + (l & 15);
    const int kb = ks * 32 + ((l >> 4) << 3);
    const float* src = W + (size_t)n * KH + kb;
    floatx4 lo = *(const floatx4*)src;
    floatx4 hi = *(const floatx4*)(src + 4);
    half8 h;
    h[0] = (_Float16)lo[0]; h[1] = (_Float16)lo[1];
    h[2] = (_Float16)lo[2]; h[3] = (_Float16)lo[3];
    h[4] = (_Float16)hi[0]; h[5] = (_Float16)hi[1];
    h[6] = (_Float16)hi[2]; h[7] = (_Float16)hi[3];
    *(half8*)(P + (size_t)u * 8) = h;                // fully coalesced 16B/lane
}

// ---- main: 2-phase staged GEMM (no store-draining barriers), LDS-bounced
// ---- linear store flush (1KB contiguous per wave-instruction) -------------
__global__ __launch_bounds__(THREADS, 2)
void lfh_main(const float* __restrict__ x, const _Float16* __restrict__ P,
              const float* __restrict__ bias, float* __restrict__ out) {
    __shared__ float Os[BM][LDSF];            // 66560 B; doubles as W stage
    _Float16* Ws = (_Float16*)&Os[0][0];      // 64 KB staging alias

    const int t   = threadIdx.x;
    const int w   = t >> 6;
    const int l   = t & 63;
    const int l15 = l & 15;
    const int lq  = l >> 4;
    const int row_in_blk = w * 16 + l15;
    const int brow = blockIdx.x * BM + row_in_blk;
    const int yeff = (int)((blockIdx.y + blockIdx.x) & (NSPLIT - 1));
    const int g0   = yeff * GPB;              // first 16-col group
    const int colBase = g0 * 16;              // first output column

    auto stage = [&](int half) {              // 64 KB: 16 x (256 thr x 16B)
        const _Float16* gsrc = P + (size_t)(g0 + half * 8) * GF16;
        #pragma unroll
        for (int r = 0; r < 16; ++r) {
            __builtin_amdgcn_global_load_lds(
                (const __attribute__((address_space(1))) void*)(gsrc + r * 2048 + t * 8),
                (__attribute__((address_space(3))) void*)(Ws + r * 2048 + t * 8),
                16, 0, 0);
        }
    };

    stage(0);

    // ---- A fragments (x rows), fp32 -> f16, overlaps staging --------------
    half8 afrag[8];
    {
        const float* xr = x + (size_t)brow * KH;
        #pragma unroll
        for (int ks = 0; ks < 8; ++ks) {
            const int kb = ks * 32 + lq * 8;
            floatx4 lo = *(const floatx4*)(xr + kb);
            floatx4 hi = *(const floatx4*)(xr + kb + 4);
            half8 f;
            f[0] = (_Float16)lo[0]; f[1] = (_Float16)lo[1];
            f[2] = (_Float16)lo[2]; f[3] = (_Float16)lo[3];
            f[4] = (_Float16)hi[0]; f[5] = (_Float16)hi[1];
            f[6] = (_Float16)hi[2]; f[7] = (_Float16)hi[3];
            afrag[ks] = f;
        }
    }

    __syncthreads();   // S1: stage(0)+afrag drained (no stores outstanding)

    floatx4 acc[GPB];
    #pragma unroll
    for (int g = 0; g < 8; ++g) {             // compute half 0
        const _Float16* fb = Ws + g * GF16 + l * 8;
        floatx4 a = (floatx4)0.0f;
        #pragma unroll
        for (int ks = 0; ks < 8; ++ks)
            a = __builtin_amdgcn_mfma_f32_16x16x32_f16(
                    *(const half8*)(fb + ks * 512), afrag[ks], a, 0, 0, 0);
        acc[g] = a;
    }

    __syncthreads();   // S2: all waves done reading half 0 (lgkm only, free)
    stage(1);
    __syncthreads();   // S3: half 1 visible (drains staging loads only)

    #pragma unroll
    for (int g = 0; g < 8; ++g) {             // compute half 1
        const _Float16* fb = Ws + g * GF16 + l * 8;
        floatx4 a = (floatx4)0.0f;
        #pragma unroll
        for (int ks = 0; ks < 8; ++ks)
            a = __builtin_amdgcn_mfma_f32_16x16x32_f16(
                    *(const half8*)(fb + ks * 512), afrag[ks], a, 0, 0, 0);
        acc[8 + g] = a;
    }

    __syncthreads();   // S4: half-1 LDS reads done -> Os writable (free)

    // ---- bias + sigmoid, bounce to LDS in out-row-major layout ------------
    #pragma unroll
    for (int g = 0; g < GPB; ++g) {
        const int c = g * 16 + lq * 4;        // col within block window
        floatx4 bv = *(const floatx4*)(bias + colBase + c);
        floatx4 r;
        #pragma unroll
        for (int j = 0; j < 4; ++j)
            r[j] = __builtin_amdgcn_rcpf(1.0f + __expf(-(acc[g][j] + bv[j])));
        *(floatx4*)&Os[row_in_blk][c] = r;
    }

    __syncthreads();   // S5: bounce complete (lgkm only, free)

    // ---- linear flush: each wave-instruction stores 1KB contiguous --------
    const float* ob = out + (size_t)blockIdx.x * BM * NN + colBase;
    #pragma unroll
    for (int i = 0; i < 16; ++i) {
        const int flat = i * 4096 + t * 16;   // byte within 64KB logical tile
        const int rrow = flat >> 10;          // 0..63
        const int cb   = flat & 1023;         // byte within 1KB row window
        floatx4 v = *(const floatx4*)((const char*)&Os[rrow][0] + cb);
        *(floatx4*)((char*)(ob + (size_t)rrow * NN) + cb) = v;   // plain store
    }
}

extern "C" void kernel_launch(void* const* d_in, const int* in_sizes, int n_in,
                              void* d_out, int out_size, void* d_ws, size_t ws_size,
                              hipStream_t stream) {
    const float* x = (const float*)d_in[0];
    const float* W = (const float*)d_in[1];
    const float* b = (const float*)d_in[2];
    float* out = (float*)d_out;
    _Float16* P = (_Float16*)d_ws;            // 512 KB packed f16 W

    pack_w<<<dim3(128), dim3(256), 0, stream>>>(W, P);

    const int Btot = in_sizes[0] / KH;        // 32768
    lfh_main<<<dim3(Btot / BM, NSPLIT), dim3(THREADS), 0, stream>>>(x, P, b, out);
}

// Round 7
// 52.839 us; speedup vs baseline: 1.4754x; 1.2346x over previous
//
#include <hip/hip_runtime.h>
#include <hip/hip_fp16.h>

typedef _Float16 half8 __attribute__((ext_vector_type(8)));
typedef float floatx4 __attribute__((ext_vector_type(4)));

#define KH 256              // H (inner / K dim)
#define NN 1024             // N heads
#define BM 64               // b-rows per block (4 waves x 16)
#define THREADS 256
#define NTILES 16           // 64-col tiles covering N
#define TILE_F16 16384      // 4 groups x 4096 f16 = 32 KB per tile

// ---------------- pack kernel: W fp32 -> f16, MFMA-fragment order ----------
// packed f16 index: ((g*8 + ks)*64 + lane)*8 + j
//   where n = g*16 + (lane&15), k = ks*32 + (lane>>4)*8 + j
__global__ __launch_bounds__(256)
void pack_w(const float* __restrict__ W, _Float16* __restrict__ P) {
    const int u  = blockIdx.x * 256 + threadIdx.x;   // 32768 threads total
    const int g  = u >> 9;
    const int ks = (u >> 6) & 7;
    const int l  = u & 63;
    const int n  = g * 16 + (l & 15);
    const int kb = ks * 32 + ((l >> 4) << 3);
    const float* src = W + (size_t)n * KH + kb;
    floatx4 lo = *(const floatx4*)src;
    floatx4 hi = *(const floatx4*)(src + 4);
    half8 h;
    h[0] = (_Float16)lo[0]; h[1] = (_Float16)lo[1];
    h[2] = (_Float16)lo[2]; h[3] = (_Float16)lo[3];
    h[4] = (_Float16)hi[0]; h[5] = (_Float16)hi[1];
    h[6] = (_Float16)hi[2]; h[7] = (_Float16)hi[3];
    *(half8*)(P + (size_t)u * 8) = h;                // fully coalesced 16B/lane
}

// ---- main: R2 structure + counted vmcnt(4) barriers (stores never drain) --
__global__ __launch_bounds__(THREADS, 2)
void lfh_main(const float* __restrict__ x, const _Float16* __restrict__ P,
              const float* __restrict__ bias, float* __restrict__ out) {
    __shared__ _Float16 WsA[TILE_F16];    // 32 KB — statically distinct
    __shared__ _Float16 WsB[TILE_F16];    // 32 KB    buffers: provably no alias
    __shared__ float    bls[NN];          // 4 KB bias (keeps loop VMEM = stage+stores only)

    const int t   = threadIdx.x;
    const int w   = t >> 6;
    const int l   = t & 63;
    const int l15 = l & 15;
    const int lq  = l >> 4;
    const int brow = blockIdx.x * BM + w * 16 + l15;

    auto stage = [&](int tile, _Float16* dst) {   // 32 KB: 8 x (256 thr x 16B)
        const _Float16* gsrc = P + (size_t)tile * TILE_F16;
        #pragma unroll
        for (int r = 0; r < 8; ++r) {
            __builtin_amdgcn_global_load_lds(
                (const __attribute__((address_space(1))) void*)(gsrc + r * 2048 + t * 8),
                (__attribute__((address_space(3))) void*)(dst + r * 2048 + t * 8),
                16, 0, 0);
        }
    };

    stage(0, WsA);

    // bias -> LDS (once)
    *(floatx4*)&bls[t * 4] = *(const floatx4*)(bias + t * 4);

    // ---- A fragments (x rows), fp32 -> f16, overlaps staging --------------
    half8 afrag[8];
    {
        const float* xr = x + (size_t)brow * KH;
        #pragma unroll
        for (int ks = 0; ks < 8; ++ks) {
            const int kb = ks * 32 + lq * 8;
            floatx4 lo = *(const floatx4*)(xr + kb);
            floatx4 hi = *(const floatx4*)(xr + kb + 4);
            half8 f;
            f[0] = (_Float16)lo[0]; f[1] = (_Float16)lo[1];
            f[2] = (_Float16)lo[2]; f[3] = (_Float16)lo[3];
            f[4] = (_Float16)hi[0]; f[5] = (_Float16)hi[1];
            f[6] = (_Float16)hi[2]; f[7] = (_Float16)hi[3];
            afrag[ks] = f;
        }
    }

    __syncthreads();    // prologue only: no stores outstanding, full drain is cheap

    float* orow = out + (size_t)brow * NN;

    #pragma unroll
    for (int tt = 0; tt < NTILES; ++tt) {
        _Float16* RB = (tt & 1) ? WsB : WsA;   // folds to static arrays on unroll
        _Float16* SB = (tt & 1) ? WsA : WsB;
        const bool last = (tt == NTILES - 1);

        if (!last) stage(tt + 1, SB);          // 8 vmem loads, oldest in FIFO
        __builtin_amdgcn_sched_barrier(0);     // pin them before compute/stores

        #pragma unroll
        for (int g = 0; g < 4; ++g) {
            const _Float16* fb = RB + g * 4096 + l * 8;  // linear, conflict-free
            floatx4 a = (floatx4)0.0f;
            #pragma unroll
            for (int ks = 0; ks < 8; ++ks)
                a = __builtin_amdgcn_mfma_f32_16x16x32_f16(
                        *(const half8*)(fb + ks * 512), afrag[ks], a, 0, 0, 0);
            const int nb = (tt * 4 + g) * 16 + lq * 4;
            floatx4 bv = *(const floatx4*)&bls[nb];      // LDS broadcast (lgkm)
            floatx4 r;
            #pragma unroll
            for (int j = 0; j < 4; ++j)
                r[j] = __builtin_amdgcn_rcpf(1.0f + __expf(-(a[j] + bv[j])));
            __builtin_nontemporal_store(r, (floatx4*)(orow + nb));  // fire & forget
        }

        if (!last) {
            // wait ONLY for staging (8 oldest); this tile's 4 NT stores (newest)
            // stay in flight and drain under the next tile's compute
            asm volatile("s_waitcnt vmcnt(4)" ::: "memory");
            __builtin_amdgcn_s_barrier();
        }
    }
}

extern "C" void kernel_launch(void* const* d_in, const int* in_sizes, int n_in,
                              void* d_out, int out_size, void* d_ws, size_t ws_size,
                              hipStream_t stream) {
    const float* x = (const float*)d_in[0];
    const float* W = (const float*)d_in[1];
    const float* b = (const float*)d_in[2];
    float* out = (float*)d_out;
    _Float16* P = (_Float16*)d_ws;            // 512 KB packed f16 W

    pack_w<<<dim3(128), dim3(256), 0, stream>>>(W, P);

    const int Btot = in_sizes[0] / KH;        // 32768
    lfh_main<<<dim3(Btot / BM), dim3(THREADS), 0, stream>>>(x, P, b, out);
}